// Round 22
// baseline (494.174 us; speedup 1.0000x reference)
//
#include <hip/hip_runtime.h>
#include <hip/hip_bf16.h>
#include <stdint.h>

// Problem constants
#define B_   4
#define LQ_  2048
#define LKV_ 2048
#define E_   2048
#define AUG_ 1024
#define H_   16
#define DH_  128

typedef unsigned short u16;
typedef __bf16 bf16x8 __attribute__((ext_vector_type(8)));
typedef float f32x4 __attribute__((ext_vector_type(4)));
typedef float f32x16 __attribute__((ext_vector_type(16)));
typedef int i32x2 __attribute__((ext_vector_type(2)));

__device__ __forceinline__ u16 f2bf(float f) {
  union { float f; unsigned u; } v; v.f = f;
  unsigned r = v.u + 0x7fffu + ((v.u >> 16) & 1u);
  return (u16)(r >> 16);
}
__device__ __forceinline__ unsigned pk2(float a, float b) {
  return (unsigned)f2bf(a) | ((unsigned)f2bf(b) << 16);
}
__device__ __forceinline__ float bf2f(u16 u) {
  union { unsigned u; float f; } v; v.u = (unsigned)u << 16; return v.f;
}
// v_cvt_pk_bf16_f32: lo -> bits[15:0], hi -> bits[31:16] (no builtin on gfx950)
__device__ __forceinline__ unsigned cvtpk_bf16(float lo, float hi) {
  unsigned r;
  asm("v_cvt_pk_bf16_f32 %0, %1, %2" : "=v"(r) : "v"(lo), "v"(hi));
  return r;
}
// raw v_exp_f32 (2^x): skips libm's denormal/range fixup (~15 VALU ops/call).
__device__ __forceinline__ float fast_ex2(float x) {
  float r;
  asm("v_exp_f32 %0, %1" : "=v"(r) : "v"(x));
  return r;
}

// async global->LDS, 16B per lane. LDS dest must be wave-uniform; HW adds lane*16.
#define GLDS(gsrc, ldst)                                                        \
  __builtin_amdgcn_global_load_lds(                                             \
      (__attribute__((address_space(1))) void*)(uintptr_t)(gsrc),               \
      (__attribute__((address_space(3))) void*)(unsigned)(uintptr_t)(ldst),     \
      16, 0, 0)

// raw workgroup barrier with compiler memory-motion fences (NO vmcnt drain)
#define BARRIER()                                   \
  do {                                              \
    asm volatile("" ::: "memory");                  \
    __builtin_amdgcn_s_barrier();                   \
    asm volatile("" ::: "memory");                  \
  } while (0)

// ------------------------------------------- fused cast f32->bf16 (5 tensors)
__global__ __launch_bounds__(256) void cast5(const float* __restrict__ p0, u16* __restrict__ o0, int c0,
                                             const float* __restrict__ p1, u16* __restrict__ o1, int c1,
                                             const float* __restrict__ p2, u16* __restrict__ o2, int c2,
                                             const float* __restrict__ p3, u16* __restrict__ o3, int c3,
                                             const float* __restrict__ p4, u16* __restrict__ o4, int c4) {
  int stride = gridDim.x * blockDim.x;
  for (int i = blockIdx.x * blockDim.x + threadIdx.x; i < c4; i += stride) {
    const float* in; u16* out; int j;
    if (i < c0)      { in = p0; out = o0; j = i; }
    else if (i < c1) { in = p1; out = o1; j = i - c0; }
    else if (i < c2) { in = p2; out = o2; j = i - c1; }
    else if (i < c3) { in = p3; out = o3; j = i - c2; }
    else             { in = p4; out = o4; j = i - c3; }
    const float4* p = (const float4*)in + (size_t)j * 2;
    float4 a = p[0], b = p[1];
    uint4 o;
    o.x = pk2(a.x, a.y); o.y = pk2(a.z, a.w);
    o.z = pk2(b.x, b.y); o.w = pk2(b.z, b.w);
    ((uint4*)out)[j] = o;
  }
}

// ------------------------------------------------- GEMM: C[M,N] = A[M,K]*W[N,K]^T + bias
// 256x256 tile, 8 waves (2M x 4N), BK=64 per barrier phase (two 32-col halves),
// double-buffered LDS (128 KiB). Per-tile overhead (barrier+vmcnt) halved vs
// BK=32 ring-of-3 -- per-tile cost was ~940ns regardless of shape (overhead-
// bound, MFMA floor ~215ns). Schedule per tile t:
//   vmcnt(0) [own tile-t loads done, issued 1 tile ago >> HBM latency]
//   BARRIER  [all waves' loads visible; all waves done reading buf^1 at t-1]
//   STAGE(t+1 -> buf^1)  [hides under compute below]
//   compute halves 0,1 from buf
// OUTMODE: 0 = bf16 row-major; 2 = bf16 scatter into vt[b,h,d,kv].
template <int OUTMODE>
__global__ __launch_bounds__(512, 2) void gemm_bt2(const u16* __restrict__ A,
                                                   const u16* __restrict__ W,
                                                   const float* __restrict__ bias,
                                                   void* __restrict__ Cp,
                                                   int N, int K) {
  __shared__ __align__(16) u16 As[2][256 * 64];
  __shared__ __align__(16) u16 Bs[2][256 * 64];
  const int tid = threadIdx.x;
  const int wave = tid >> 6, lane = tid & 63;
  const int wr = wave >> 2, wc = wave & 3;          // 2 x 4 wave grid
  const int g = lane >> 4, r16 = lane & 15;
  const int m0 = blockIdx.y << 8, n0 = blockIdx.x << 8;

  size_t gA[2], gB[2];
  int ldst[2];
#pragma unroll
  for (int i = 0; i < 2; ++i) {
    int c = tid + i * 512;
    int s = c >> 6, w = c & 63;
    int wp = w ^ (((w >> 5) & 1) << 1);
    int grow = s * 16 + (wp >> 2);
    int gcol = (wp & 3) * 8;
    gA[i] = (size_t)(m0 + grow) * K + gcol;
    gB[i] = (size_t)(n0 + grow) * K + gcol;
    ldst[i] = c * 8;  // u16 elements (16B chunks)
  }
  const int aoff = r16 * 32 + ((g * 8) ^ ((r16 & 8) ? 16 : 0));

  f32x4 acc[8][4];
#pragma unroll
  for (int m = 0; m < 8; ++m)
#pragma unroll
    for (int n = 0; n < 4; ++n) acc[m][n] = (f32x4){0.f, 0.f, 0.f, 0.f};

  const int NT = K >> 6;  // BK=64 tiles

  // stage BK=64 tile kt into buffer buf (8 GLDS per thread)
  auto STAGE = [&](int kt, int buf) {
    size_t k0 = (size_t)kt * 64;
#pragma unroll
    for (int hh = 0; hh < 2; ++hh) {
#pragma unroll
      for (int i = 0; i < 2; ++i) {
        GLDS(A + gA[i] + k0 + hh * 32, &As[buf][hh * 8192 + ldst[i]]);
        GLDS(W + gB[i] + k0 + hh * 32, &Bs[buf][hh * 8192 + ldst[i]]);
      }
    }
  };

  STAGE(0, 0);
  int cur = 0;
  for (int t = 0; t < NT; ++t) {
    asm volatile("s_waitcnt vmcnt(0)" ::: "memory");  // own tile-t loads done
    BARRIER();  // tile t visible; buf^1 reads (t-1) finished by all waves
    if (t + 1 < NT) STAGE(t + 1, cur ^ 1);

#pragma unroll
    for (int hh = 0; hh < 2; ++hh) {
      const u16* as = &As[cur][hh * 8192];
      const u16* bs = &Bs[cur][hh * 8192];
      bf16x8 bfr[4], af[4];
#pragma unroll
      for (int n = 0; n < 4; ++n)
        bfr[n] = *(const bf16x8*)&bs[wc * 2048 + n * 512 + aoff];
#pragma unroll
      for (int m = 0; m < 4; ++m)
        af[m] = *(const bf16x8*)&as[wr * 4096 + m * 512 + aoff];
      __builtin_amdgcn_s_setprio(1);
#pragma unroll
      for (int m = 0; m < 4; ++m)
#pragma unroll
        for (int n = 0; n < 4; ++n)
          acc[m][n] = __builtin_amdgcn_mfma_f32_16x16x32_bf16(af[m], bfr[n], acc[m][n], 0, 0, 0);
      __builtin_amdgcn_s_setprio(0);

      bf16x8 af2[4];
#pragma unroll
      for (int m = 0; m < 4; ++m)
        af2[m] = *(const bf16x8*)&as[wr * 4096 + (m + 4) * 512 + aoff];
      __builtin_amdgcn_s_setprio(1);
#pragma unroll
      for (int m = 0; m < 4; ++m)
#pragma unroll
        for (int n = 0; n < 4; ++n)
          acc[m + 4][n] = __builtin_amdgcn_mfma_f32_16x16x32_bf16(af2[m], bfr[n], acc[m + 4][n], 0, 0, 0);
      __builtin_amdgcn_s_setprio(0);
    }
    cur ^= 1;
  }

  float bv[4];
#pragma unroll
  for (int n = 0; n < 4; ++n)
    bv[n] = bias ? bias[n0 + wc * 64 + n * 16 + r16] : 0.f;
#pragma unroll
  for (int m = 0; m < 8; ++m) {
    int row = m0 + wr * 128 + m * 16 + g * 4;
#pragma unroll
    for (int n = 0; n < 4; ++n) {
      int col = n0 + wc * 64 + n * 16 + r16;
      if (OUTMODE == 2) {
        // vt[((b*16+h)*128+d)*2048 + kv], b=row>>11, kv=row&2047, h=col>>7, d=col&127
        size_t base = (((size_t)((row >> 11) * 16 + (col >> 7)) * 128 + (col & 127)) << 11) + (row & 2047);
        uint2 o2;
        o2.x = pk2(acc[m][n][0] + bv[n], acc[m][n][1] + bv[n]);
        o2.y = pk2(acc[m][n][2] + bv[n], acc[m][n][3] + bv[n]);
        *(uint2*)&((u16*)Cp)[base] = o2;
      } else {
#pragma unroll
        for (int r = 0; r < 4; ++r) {
          float v = acc[m][n][r] + bv[n];
          ((u16*)Cp)[(size_t)(row + r) * N + col] = f2bf(v);
        }
      }
    }
  }
}

// ------------------------------------------------- generic bf16 transpose: in[R][C] -> out[C][R]
__global__ __launch_bounds__(256) void transpose_w(const u16* __restrict__ in,
                                                   u16* __restrict__ out,
                                                   int R, int C) {
  __shared__ __align__(16) u16 t[64][72];
  int tid = threadIdx.x;
  int c0 = blockIdx.x << 6, r0 = blockIdx.y << 6;
  int gr = tid & 7, rw = tid >> 3;  // rw 0..31
#pragma unroll
  for (int p = 0; p < 2; ++p) {
    int row = rw + p * 32;
    uint4 x = *(const uint4*)&in[(size_t)(r0 + row) * C + c0 + gr * 8];
    *(uint4*)&t[row][gr * 8] = x;
  }
  __syncthreads();
#pragma unroll
  for (int p = 0; p < 2; ++p) {
    int d = rw + p * 32;  // col-local
    u16 tmp[8];
#pragma unroll
    for (int j = 0; j < 8; ++j) tmp[j] = t[gr * 8 + j][d];
    uint4 o;
    o.x = (unsigned)tmp[0] | ((unsigned)tmp[1] << 16);
    o.y = (unsigned)tmp[2] | ((unsigned)tmp[3] << 16);
    o.z = (unsigned)tmp[4] | ((unsigned)tmp[5] << 16);
    o.w = (unsigned)tmp[6] | ((unsigned)tmp[7] << 16);
    *(uint4*)&out[(size_t)(c0 + d) * R + r0 + gr * 8] = o;
  }
}

// ------------------------------------------------- bias GEMV: out[i] = W[i,:] . pb + base[i]
__global__ __launch_bounds__(256) void gemv_bias(const u16* __restrict__ W,
                                                 const float* __restrict__ pb,
                                                 const float* __restrict__ base,
                                                 float* __restrict__ out, int K) {
  int row = blockIdx.x, tid = threadIdx.x;
  uint4 wv = ((const uint4*)(W + (size_t)row * K))[tid];  // 8 bf16
  const float4* pb4 = (const float4*)pb;
  float4 p0 = pb4[tid * 2], p1 = pb4[tid * 2 + 1];
  float s = bf2f((u16)(wv.x & 0xffff)) * p0.x + bf2f((u16)(wv.x >> 16)) * p0.y +
            bf2f((u16)(wv.y & 0xffff)) * p0.z + bf2f((u16)(wv.y >> 16)) * p0.w +
            bf2f((u16)(wv.z & 0xffff)) * p1.x + bf2f((u16)(wv.z >> 16)) * p1.y +
            bf2f((u16)(wv.w & 0xffff)) * p1.z + bf2f((u16)(wv.w >> 16)) * p1.w;
  s += __shfl_xor(s, 1);  s += __shfl_xor(s, 2);
  s += __shfl_xor(s, 4);  s += __shfl_xor(s, 8);
  s += __shfl_xor(s, 16); s += __shfl_xor(s, 32);
  __shared__ float ls[4];
  if ((tid & 63) == 0) ls[tid >> 6] = s;
  __syncthreads();
  if (tid == 0) out[row] = ls[0] + ls[1] + ls[2] + ls[3] + base[row];
}

// ------------------------------------------------- flash attention (round-14 config, validated 145us)
__global__ __launch_bounds__(256) void attn_kernel(const u16* __restrict__ Q,
                                                   const u16* __restrict__ K,
                                                   const u16* __restrict__ Vt,
                                                   u16* __restrict__ Octx) {
  __shared__ __align__(16) u16 Ks[2][64 * 128];
  __shared__ __align__(16) u16 Vs[2][128 * 64];
  const int tid = threadIdx.x, wave = tid >> 6, lane = tid & 63;
  const int bid = blockIdx.x;
  const int qb = bid & 15, bh = bid >> 4, b = bh >> 4, h = bh & 15;
  const int q0 = qb << 7;
  const int l31 = lane & 31, hi = lane >> 5;
  const float Cs = 0.08838834764831845f * 1.4426950408889634f;  // 1/sqrt(128)*log2(e)

  const u16* Qp = Q + ((size_t)(b * LQ_ + q0 + wave * 32 + l31)) * E_ + h * DH_;
  const u16* Kp = K + ((size_t)(b * LKV_)) * E_ + h * DH_;
  const u16* Vp = Vt + (size_t)bh * DH_ * LKV_;

  const int kl_row = lane >> 4, kl_g = lane & 15;  // K stage: 4 rows of 256B
  const int vl_row = lane >> 3, vl_g = lane & 7;   // V stage: 8 rows of 128B

  // Q B-frags: col=q=l31, k=dh=c*16+hi*8+j; prescaled by Cs.
  bf16x8 qf[8];
#pragma unroll
  for (int c = 0; c < 8; ++c) {
    bf16x8 raw = *(const bf16x8*)&Qp[c * 16 + hi * 8];
#pragma unroll
    for (int j = 0; j < 8; ++j) qf[c][j] = (__bf16)((float)raw[j] * Cs);
  }

  // all-ones B-fragment for the row-sum MFMA
  bf16x8 VONES;
#pragma unroll
  for (int j = 0; j < 8; ++j) VONES[j] = (__bf16)1.0f;
  // loop-invariant zero C-operand (kills per-tile st zero-init movs)
  f32x16 FZERO = {};

  f32x16 o[4];
#pragma unroll
  for (int d = 0; d < 4; ++d)
#pragma unroll
    for (int r = 0; r < 16; ++r) o[d][r] = 0.f;
  f32x16 ol = {};  // row-sums accumulator (same C-layout as o)

  // stage kv-tile (8 global_load_lds) into buffer `buf`
  auto STAGE = [&](int kv0, int buf) {
#pragma unroll
    for (int j = 0; j < 4; ++j) {
      int cc = wave * 4 + j;
      int krow = cc * 4 + kl_row;
      GLDS(Kp + (size_t)(kv0 + krow) * E_ + ((kl_g ^ (krow & 15)) << 3), &Ks[buf][cc * 512]);
      int vrow = cc * 8 + vl_row;
      GLDS(Vp + (size_t)vrow * LKV_ + kv0 + ((vl_g ^ (vrow & 7)) << 3), &Vs[buf][cc * 512]);
    }
  };

  const int NT = LKV_ / 64;
  STAGE(0, 0);

  for (int t = 0; t < NT; ++t) {
    const int cur = t & 1;
    if (t + 1 < NT) {
      STAGE((t + 1) * 64, cur ^ 1);  // buf cur^1 released by end-barrier of t-1
      asm volatile("s_waitcnt vmcnt(8)" ::: "memory");  // own tile-t loads done
    } else {
      asm volatile("s_waitcnt vmcnt(0)" ::: "memory");
    }
    BARRIER();  // all waves' tile-t loads visible

    const u16* ks = Ks[cur];
    const u16* vs = Vs[cur];

    // S^T[kv][q]: A = K rows (kv = n*32 + l31, k = dh), B = Q. c=0 peeled w/ FZERO.
    f32x16 st[2];
#pragma unroll
    for (int n = 0; n < 2; ++n) {
      int row = n * 32 + l31;
      bf16x8 kf = *(const bf16x8*)&ks[row * 128 + ((hi ^ (row & 15)) << 3)];
      st[n] = __builtin_amdgcn_mfma_f32_32x32x16_bf16(kf, qf[0], FZERO, 0, 0, 0);
    }
#pragma unroll
    for (int c = 1; c < 8; ++c) {
#pragma unroll
      for (int n = 0; n < 2; ++n) {
        int row = n * 32 + l31;
        bf16x8 kf = *(const bf16x8*)&ks[row * 128 + (((c * 2 + hi) ^ (row & 15)) << 3)];
        st[n] = __builtin_amdgcn_mfma_f32_32x32x16_bf16(kf, qf[c], st[n], 0, 0, 0);
      }
    }

    // P = exp2(S') via raw v_exp_f32, pack PV A-frags in-register.
    unsigned AF[4][4];
#pragma unroll
    for (int n = 0; n < 2; ++n) {
      float pv[16];
#pragma unroll
      for (int r = 0; r < 16; ++r) pv[r] = fast_ex2(st[n][r]);
      unsigned a0 = cvtpk_bf16(pv[0], pv[1]),   a1 = cvtpk_bf16(pv[2], pv[3]);
      unsigned a2 = cvtpk_bf16(pv[4], pv[5]),   a3 = cvtpk_bf16(pv[6], pv[7]);
      unsigned b0 = cvtpk_bf16(pv[8], pv[9]),   b1 = cvtpk_bf16(pv[10], pv[11]);
      unsigned b2 = cvtpk_bf16(pv[12], pv[13]), b3 = cvtpk_bf16(pv[14], pv[15]);
      i32x2 r02 = __builtin_amdgcn_permlane32_swap((int)a0, (int)a2, false, false);
      i32x2 r13 = __builtin_amdgcn_permlane32_swap((int)a1, (int)a3, false, false);
      AF[n * 2][0] = (unsigned)r02[0]; AF[n * 2][1] = (unsigned)r13[0];
      AF[n * 2][2] = (unsigned)r02[1]; AF[n * 2][3] = (unsigned)r13[1];
      i32x2 s02 = __builtin_amdgcn_permlane32_swap((int)b0, (int)b2, false, false);
      i32x2 s13 = __builtin_amdgcn_permlane32_swap((int)b1, (int)b3, false, false);
      AF[n * 2 + 1][0] = (unsigned)s02[0]; AF[n * 2 + 1][1] = (unsigned)s13[0];
      AF[n * 2 + 1][2] = (unsigned)s02[1]; AF[n * 2 + 1][3] = (unsigned)s13[1];
    }

    // PV: A = P[q][kv-step], B = Vt[d][kv]; plus ones-B MFMA for row sums.
#pragma unroll
    for (int s = 0; s < 4; ++s) {
      union { unsigned u[4]; bf16x8 v; } pk;
      pk.u[0] = AF[s][0]; pk.u[1] = AF[s][1]; pk.u[2] = AF[s][2]; pk.u[3] = AF[s][3];
      bf16x8 pa = pk.v;
#pragma unroll
      for (int db = 0; db < 4; ++db) {
        int d = db * 32 + l31;
        bf16x8 vf = *(const bf16x8*)&vs[d * 64 + (((s * 2 + hi) ^ (d & 7)) << 3)];
        o[db] = __builtin_amdgcn_mfma_f32_32x32x16_bf16(pa, vf, o[db], 0, 0, 0);
      }
      ol = __builtin_amdgcn_mfma_f32_32x32x16_bf16(pa, VONES, ol, 0, 0, 0);
    }
    BARRIER();  // all waves done reading buf cur -> free for staging at t+1
  }

  // write ctx: li = 1/ol[r] (ol row layout == o row layout)
#pragma unroll
  for (int r = 0; r < 16; ++r) {
    int crow = (r & 3) + 8 * (r >> 2) + 4 * hi;
    float li = 1.0f / ol[r];
    size_t rb = ((size_t)(b * LQ_ + q0 + wave * 32 + crow)) * E_ + h * DH_ + l31;
#pragma unroll
    for (int db = 0; db < 4; ++db)
      Octx[rb + db * 32] = f2bf(o[db][r] * li);
  }
}

// ------------------------------------------------- RMSNorm (Gemma) + residual, bf16 input
__global__ __launch_bounds__(256) void rms_res_bf(const u16* __restrict__ x,
                                                  const float* __restrict__ w,
                                                  const float* __restrict__ qres,
                                                  float* __restrict__ out) {
  int row = blockIdx.x, tid = threadIdx.x;
  uint4 xv = ((const uint4*)(x + (size_t)row * E_))[tid];  // 8 bf16
  float xf[8];
  xf[0] = bf2f((u16)(xv.x & 0xffff)); xf[1] = bf2f((u16)(xv.x >> 16));
  xf[2] = bf2f((u16)(xv.y & 0xffff)); xf[3] = bf2f((u16)(xv.y >> 16));
  xf[4] = bf2f((u16)(xv.z & 0xffff)); xf[5] = bf2f((u16)(xv.z >> 16));
  xf[6] = bf2f((u16)(xv.w & 0xffff)); xf[7] = bf2f((u16)(xv.w >> 16));
  float ss = 0.f;
#pragma unroll
  for (int j = 0; j < 8; ++j) ss += xf[j] * xf[j];
  ss += __shfl_xor(ss, 1);  ss += __shfl_xor(ss, 2);
  ss += __shfl_xor(ss, 4);  ss += __shfl_xor(ss, 8);
  ss += __shfl_xor(ss, 16); ss += __shfl_xor(ss, 32);
  __shared__ float ls[4];
  if ((tid & 63) == 0) ls[tid >> 6] = ss;
  __syncthreads();
  float total = ls[0] + ls[1] + ls[2] + ls[3];
  float rs = rsqrtf(total * (1.0f / (float)E_) + 1e-6f);
  const float4* qr = (const float4*)(qres + (size_t)row * E_);
  const float4* wr4 = (const float4*)w;
  float4 q0 = qr[tid * 2], q1 = qr[tid * 2 + 1];
  float4 w0 = wr4[tid * 2], w1 = wr4[tid * 2 + 1];
  float4 o0, o1;
  o0.x = xf[0] * rs * (1.f + w0.x) + q0.x;
  o0.y = xf[1] * rs * (1.f + w0.y) + q0.y;
  o0.z = xf[2] * rs * (1.f + w0.z) + q0.z;
  o0.w = xf[3] * rs * (1.f + w0.w) + q0.w;
  o1.x = xf[4] * rs * (1.f + w1.x) + q1.x;
  o1.y = xf[5] * rs * (1.f + w1.y) + q1.y;
  o1.z = xf[6] * rs * (1.f + w1.z) + q1.z;
  o1.w = xf[7] * rs * (1.f + w1.w) + q1.w;
  float4* op = (float4*)(out + (size_t)row * E_);
  op[tid * 2] = o0;
  op[tid * 2 + 1] = o1;
}

// ------------------------------------------------- launcher
extern "C" void kernel_launch(void* const* d_in, const int* in_sizes, int n_in,
                              void* d_out, int out_size, void* d_ws, size_t ws_size,
                              hipStream_t stream) {
  const float* query = (const float*)d_in[0];
  const float* aug   = (const float*)d_in[1];
  // d_in[2] = aug_mask: unused by the reference forward
  const float* projw = (const float*)d_in[3];
  const float* projb = (const float*)d_in[4];
  const float* ipw   = (const float*)d_in[5];
  const float* ipb   = (const float*)d_in[6];
  const float* opw   = (const float*)d_in[7];
  const float* opb   = (const float*)d_in[8];
  const float* rmsw  = (const float*)d_in[9];

  char* ws = (char*)d_ws;
  size_t off = 0;
  auto alloc = [&](size_t bytes) {
    void* p = ws + off;
    off += (bytes + 1023) & ~(size_t)1023;
    return p;
  };
  // ws footprint unchanged from round 18 (256.2MB). Fusion scratch lives in
  // kv_bf's region; vt lives in v_bf's region (v GEMM scatters directly).
  u16* query_bf = (u16*)alloc((size_t)B_ * LQ_ * E_ * 2);        // 33.6MB
  u16* aug_bf   = (u16*)alloc((size_t)B_ * LKV_ * AUG_ * 2);     // 16.8MB
  u16* projw_bf = (u16*)alloc((size_t)E_ * AUG_ * 2);            //  4.2MB
  u16* w_bf     = (u16*)alloc((size_t)3 * E_ * E_ * 2);          // 25.2MB
  u16* outw_bf  = (u16*)alloc((size_t)E_ * E_ * 2);              //  8.4MB
  u16* kv_bf    = (u16*)alloc((size_t)B_ * LKV_ * E_ * 2);       // 33.6MB (fusion scratch)
  u16* q_bf     = (u16*)alloc((size_t)B_ * LQ_ * E_ * 2);
  u16* k_bf     = (u16*)alloc((size_t)B_ * LKV_ * E_ * 2);
  u16* v_bf     = (u16*)alloc((size_t)B_ * LKV_ * E_ * 2);       // holds vt
  u16* ctx_bf   = (u16*)alloc((size_t)B_ * LQ_ * E_ * 2);
  u16* attn_out = query_bf;            // alias: region 0 all dead by then (bf16)
  // fusion scratch carved from kv_bf (12MiB + 16KB < 32MiB):
  u16* projwT = kv_bf;                                       // AUG*E u16 = 4MiB
  u16* wkv_f  = kv_bf + (size_t)AUG_ * E_;                   // 2E*AUG u16 = 8MiB
  float* bkv  = (float*)(kv_bf + (size_t)AUG_ * E_ + (size_t)2 * E_ * AUG_);  // 16KB
  u16* vt_bf = v_bf;                   // v GEMM writes vt here directly
  (void)in_sizes; (void)n_in; (void)ws_size;

  const int M = B_ * LQ_;  // 8192

  // fused cast of all 5 f32 tensors -> bf16 (single launch)
  const int n8_q  = (int)((size_t)M * E_ / 8);
  const int n8_a  = (int)((size_t)M * AUG_ / 8);
  const int n8_pw = (int)((size_t)E_ * AUG_ / 8);
  const int n8_iw = (int)((size_t)3 * E_ * E_ / 8);
  const int n8_ow = (int)((size_t)E_ * E_ / 8);
  const int cc0 = n8_q, cc1 = cc0 + n8_a, cc2 = cc1 + n8_pw, cc3 = cc2 + n8_iw,
            cc4 = cc3 + n8_ow;
  cast5<<<2048, 256, 0, stream>>>(query, query_bf, cc0,
                                  aug, aug_bf, cc1,
                                  projw, projw_bf, cc2,
                                  ipw, w_bf, cc3,
                                  opw, outw_bf, cc4);

  // projwT[AUG,E] = projw^T
  transpose_w<<<dim3(AUG_ / 64, E_ / 64), 256, 0, stream>>>(projw_bf, projwT, E_, AUG_);
  // Wkv[2E, AUG] = [wk; wv] @ projw  (weight-space fusion)
  gemm_bt2<0><<<dim3(AUG_ / 256, (2 * E_) / 256), 512, 0, stream>>>(
      w_bf + (size_t)E_ * E_, projwT, nullptr, wkv_f, AUG_, E_);
  // bkv[2E] = [wk; wv] @ projb + ipb[E..3E]
  gemv_bias<<<2 * E_, 256, 0, stream>>>(w_bf + (size_t)E_ * E_, projb, ipb + E_, bkv, E_);

  // q = query @ wq^T + bq
  gemm_bt2<0><<<dim3(E_ / 256, M / 256), 512, 0, stream>>>(query_bf, w_bf, ipb, q_bf, E_, E_);
  // k = aug @ Wk_f^T + bk'   (K = AUG = 1024)
  gemm_bt2<0><<<dim3(E_ / 256, M / 256), 512, 0, stream>>>(aug_bf, wkv_f, bkv, k_bf, E_, AUG_);
  // vt[b,h,d,kv] = (aug @ Wv_f^T + bv')^T  -- scatter epilogue, no transpose pass
  gemm_bt2<2><<<dim3(E_ / 256, M / 256), 512, 0, stream>>>(
      aug_bf, wkv_f + (size_t)E_ * AUG_, bkv + E_, vt_bf, E_, AUG_);
  // attention -> ctx  (QBLK=128 per block)
  attn_kernel<<<B_ * H_ * (LQ_ / 128), 256, 0, stream>>>(q_bf, k_bf, vt_bf, ctx_bf);
  // attn_out = ctx @ out_proj^T + b (bf16)
  gemm_bt2<0><<<dim3(E_ / 256, M / 256), 512, 0, stream>>>(ctx_bf, outw_bf, opb, attn_out, E_, E_);
  // out = RMSNorm(attn_out)*(1+w) + query
  rms_res_bf<<<M, 256, 0, stream>>>(attn_out, rmsw, query, (float*)d_out);
}

// Round 23
// 468.107 us; speedup vs baseline: 1.0557x; 1.0557x over previous
//
#include <hip/hip_runtime.h>
#include <hip/hip_bf16.h>
#include <stdint.h>

// Problem constants
#define B_   4
#define LQ_  2048
#define LKV_ 2048
#define E_   2048
#define AUG_ 1024
#define H_   16
#define DH_  128

typedef unsigned short u16;
typedef __bf16 bf16x8 __attribute__((ext_vector_type(8)));
typedef float f32x4 __attribute__((ext_vector_type(4)));
typedef float f32x16 __attribute__((ext_vector_type(16)));
typedef int i32x2 __attribute__((ext_vector_type(2)));

__device__ __forceinline__ u16 f2bf(float f) {
  union { float f; unsigned u; } v; v.f = f;
  unsigned r = v.u + 0x7fffu + ((v.u >> 16) & 1u);
  return (u16)(r >> 16);
}
__device__ __forceinline__ unsigned pk2(float a, float b) {
  return (unsigned)f2bf(a) | ((unsigned)f2bf(b) << 16);
}
__device__ __forceinline__ float bf2f(u16 u) {
  union { unsigned u; float f; } v; v.u = (unsigned)u << 16; return v.f;
}
// v_cvt_pk_bf16_f32: lo -> bits[15:0], hi -> bits[31:16] (no builtin on gfx950)
__device__ __forceinline__ unsigned cvtpk_bf16(float lo, float hi) {
  unsigned r;
  asm("v_cvt_pk_bf16_f32 %0, %1, %2" : "=v"(r) : "v"(lo), "v"(hi));
  return r;
}
// raw v_exp_f32 (2^x): skips libm's denormal/range fixup (~15 VALU ops/call).
__device__ __forceinline__ float fast_ex2(float x) {
  float r;
  asm("v_exp_f32 %0, %1" : "=v"(r) : "v"(x));
  return r;
}

// async global->LDS, 16B per lane. LDS dest must be wave-uniform; HW adds lane*16.
#define GLDS(gsrc, ldst)                                                        \
  __builtin_amdgcn_global_load_lds(                                             \
      (__attribute__((address_space(1))) void*)(uintptr_t)(gsrc),               \
      (__attribute__((address_space(3))) void*)(unsigned)(uintptr_t)(ldst),     \
      16, 0, 0)

// raw workgroup barrier with compiler memory-motion fences (NO vmcnt drain)
#define BARRIER()                                   \
  do {                                              \
    asm volatile("" ::: "memory");                  \
    __builtin_amdgcn_s_barrier();                   \
    asm volatile("" ::: "memory");                  \
  } while (0)

// ------------------------------------------- fused cast f32->bf16 (5 tensors)
__global__ __launch_bounds__(256) void cast5(const float* __restrict__ p0, u16* __restrict__ o0, int c0,
                                             const float* __restrict__ p1, u16* __restrict__ o1, int c1,
                                             const float* __restrict__ p2, u16* __restrict__ o2, int c2,
                                             const float* __restrict__ p3, u16* __restrict__ o3, int c3,
                                             const float* __restrict__ p4, u16* __restrict__ o4, int c4) {
  int stride = gridDim.x * blockDim.x;
  for (int i = blockIdx.x * blockDim.x + threadIdx.x; i < c4; i += stride) {
    const float* in; u16* out; int j;
    if (i < c0)      { in = p0; out = o0; j = i; }
    else if (i < c1) { in = p1; out = o1; j = i - c0; }
    else if (i < c2) { in = p2; out = o2; j = i - c1; }
    else if (i < c3) { in = p3; out = o3; j = i - c2; }
    else             { in = p4; out = o4; j = i - c3; }
    const float4* p = (const float4*)in + (size_t)j * 2;
    float4 a = p[0], b = p[1];
    uint4 o;
    o.x = pk2(a.x, a.y); o.y = pk2(a.z, a.w);
    o.z = pk2(b.x, b.y); o.w = pk2(b.z, b.w);
    ((uint4*)out)[j] = o;
  }
}

// ------------------------------------------------- GEMM: C[M,N] = A[M,K]*W[N,K]^T + bias
// 256x256 tile, 8 waves (2M x 4N), BK=32, ring-of-3 K-tile LDS pipeline (96 KiB).
// SINGLE barrier/tile (validated round 18). vmcnt(4) counted, never 0 mid-loop.
// (Round-22 lesson: BK=64 dbuf with vmcnt(0) drain regressed -- the ring's
// 2-tile prefetch distance + counted wait is what hides staging latency.)
// OUTMODE: 0 = bf16 row-major C[M][N]; 2 = bf16 scatter into vt[b,h,d,kv]
// (row = b*2048+kv, col = h*128+d; per-thread r=0..3 are consecutive kv ->
// one packed uint2 store). M-tiles never cross batch (2048 % 256 == 0).
template <int OUTMODE>
__global__ __launch_bounds__(512, 2) void gemm_bt2(const u16* __restrict__ A,
                                                   const u16* __restrict__ W,
                                                   const float* __restrict__ bias,
                                                   void* __restrict__ Cp,
                                                   int N, int K) {
  __shared__ __align__(16) u16 As[3][256 * 32];
  __shared__ __align__(16) u16 Bs[3][256 * 32];
  const int tid = threadIdx.x;
  const int wave = tid >> 6, lane = tid & 63;
  const int wr = wave >> 2, wc = wave & 3;          // 2 x 4 wave grid
  const int g = lane >> 4, r16 = lane & 15;
  const int m0 = blockIdx.y << 8, n0 = blockIdx.x << 8;

  size_t gA[2], gB[2];
  int ldst[2];
#pragma unroll
  for (int i = 0; i < 2; ++i) {
    int c = tid + i * 512;
    int s = c >> 6, w = c & 63;
    int wp = w ^ (((w >> 5) & 1) << 1);
    int grow = s * 16 + (wp >> 2);
    int gcol = (wp & 3) * 8;
    gA[i] = (size_t)(m0 + grow) * K + gcol;
    gB[i] = (size_t)(n0 + grow) * K + gcol;
    ldst[i] = c * 8;  // u16 elements (16B chunks)
  }
  const int aoff = r16 * 32 + ((g * 8) ^ ((r16 & 8) ? 16 : 0));

  f32x4 acc[8][4];
#pragma unroll
  for (int m = 0; m < 8; ++m)
#pragma unroll
    for (int n = 0; n < 4; ++n) acc[m][n] = (f32x4){0.f, 0.f, 0.f, 0.f};

  const int NT = K >> 5;
#pragma unroll
  for (int i = 0; i < 2; ++i) GLDS(A + gA[i], &As[0][ldst[i]]);
#pragma unroll
  for (int i = 0; i < 2; ++i) GLDS(W + gB[i], &Bs[0][ldst[i]]);
#pragma unroll
  for (int i = 0; i < 2; ++i) GLDS(A + gA[i] + 32, &As[1][ldst[i]]);
#pragma unroll
  for (int i = 0; i < 2; ++i) GLDS(W + gB[i] + 32, &Bs[1][ldst[i]]);

  int cur = 0;
  for (int t = 0; t < NT; ++t) {
    if (t + 1 < NT)
      asm volatile("s_waitcnt vmcnt(4)" ::: "memory");
    else
      asm volatile("s_waitcnt vmcnt(0)" ::: "memory");
    BARRIER();  // top barrier: tile t visible; also fences slot (t+2)%3 reuse

    const u16* as = As[cur];
    const u16* bs = Bs[cur];
    int nxt = cur + 2; if (nxt >= 3) nxt -= 3;

    bf16x8 bfr[4], af[4];
#pragma unroll
    for (int n = 0; n < 4; ++n)
      bfr[n] = *(const bf16x8*)&bs[wc * 2048 + n * 512 + aoff];
#pragma unroll
    for (int m = 0; m < 4; ++m)
      af[m] = *(const bf16x8*)&as[wr * 4096 + m * 512 + aoff];
    if (t + 2 < NT) {
      size_t k0 = (size_t)(t + 2) * 32;
#pragma unroll
      for (int i = 0; i < 2; ++i) GLDS(A + gA[i] + k0, &As[nxt][ldst[i]]);
    }
    __builtin_amdgcn_s_setprio(1);
#pragma unroll
    for (int m = 0; m < 4; ++m)
#pragma unroll
      for (int n = 0; n < 4; ++n)
        acc[m][n] = __builtin_amdgcn_mfma_f32_16x16x32_bf16(af[m], bfr[n], acc[m][n], 0, 0, 0);
    __builtin_amdgcn_s_setprio(0);

    bf16x8 af2[4];
#pragma unroll
    for (int m = 0; m < 4; ++m)
      af2[m] = *(const bf16x8*)&as[wr * 4096 + (m + 4) * 512 + aoff];
    if (t + 2 < NT) {
      size_t k0 = (size_t)(t + 2) * 32;
#pragma unroll
      for (int i = 0; i < 2; ++i) GLDS(W + gB[i] + k0, &Bs[nxt][ldst[i]]);
    }
    __builtin_amdgcn_s_setprio(1);
#pragma unroll
    for (int m = 0; m < 4; ++m)
#pragma unroll
      for (int n = 0; n < 4; ++n)
        acc[m + 4][n] = __builtin_amdgcn_mfma_f32_16x16x32_bf16(af2[m], bfr[n], acc[m + 4][n], 0, 0, 0);
    __builtin_amdgcn_s_setprio(0);

    cur = cur + 1; if (cur >= 3) cur -= 3;
  }

  float bv[4];
#pragma unroll
  for (int n = 0; n < 4; ++n)
    bv[n] = bias ? bias[n0 + wc * 64 + n * 16 + r16] : 0.f;
#pragma unroll
  for (int m = 0; m < 8; ++m) {
    int row = m0 + wr * 128 + m * 16 + g * 4;
#pragma unroll
    for (int n = 0; n < 4; ++n) {
      int col = n0 + wc * 64 + n * 16 + r16;
      if (OUTMODE == 2) {
        // vt[((b*16+h)*128+d)*2048 + kv], b=row>>11, kv=row&2047, h=col>>7, d=col&127
        size_t base = (((size_t)((row >> 11) * 16 + (col >> 7)) * 128 + (col & 127)) << 11) + (row & 2047);
        uint2 o2;
        o2.x = pk2(acc[m][n][0] + bv[n], acc[m][n][1] + bv[n]);
        o2.y = pk2(acc[m][n][2] + bv[n], acc[m][n][3] + bv[n]);
        *(uint2*)&((u16*)Cp)[base] = o2;
      } else {
#pragma unroll
        for (int r = 0; r < 4; ++r) {
          float v = acc[m][n][r] + bv[n];
          ((u16*)Cp)[(size_t)(row + r) * N + col] = f2bf(v);
        }
      }
    }
  }
}

// ------------------------------------------------- generic bf16 transpose: in[R][C] -> out[C][R]
__global__ __launch_bounds__(256) void transpose_w(const u16* __restrict__ in,
                                                   u16* __restrict__ out,
                                                   int R, int C) {
  __shared__ __align__(16) u16 t[64][72];
  int tid = threadIdx.x;
  int c0 = blockIdx.x << 6, r0 = blockIdx.y << 6;
  int gr = tid & 7, rw = tid >> 3;  // rw 0..31
#pragma unroll
  for (int p = 0; p < 2; ++p) {
    int row = rw + p * 32;
    uint4 x = *(const uint4*)&in[(size_t)(r0 + row) * C + c0 + gr * 8];
    *(uint4*)&t[row][gr * 8] = x;
  }
  __syncthreads();
#pragma unroll
  for (int p = 0; p < 2; ++p) {
    int d = rw + p * 32;  // col-local
    u16 tmp[8];
#pragma unroll
    for (int j = 0; j < 8; ++j) tmp[j] = t[gr * 8 + j][d];
    uint4 o;
    o.x = (unsigned)tmp[0] | ((unsigned)tmp[1] << 16);
    o.y = (unsigned)tmp[2] | ((unsigned)tmp[3] << 16);
    o.z = (unsigned)tmp[4] | ((unsigned)tmp[5] << 16);
    o.w = (unsigned)tmp[6] | ((unsigned)tmp[7] << 16);
    *(uint4*)&out[(size_t)(c0 + d) * R + r0 + gr * 8] = o;
  }
}

// ------------------------------------------------- bias GEMV: out[i] = W[i,:] . pb + base[i]
__global__ __launch_bounds__(256) void gemv_bias(const u16* __restrict__ W,
                                                 const float* __restrict__ pb,
                                                 const float* __restrict__ base,
                                                 float* __restrict__ out, int K) {
  int row = blockIdx.x, tid = threadIdx.x;
  uint4 wv = ((const uint4*)(W + (size_t)row * K))[tid];  // 8 bf16
  const float4* pb4 = (const float4*)pb;
  float4 p0 = pb4[tid * 2], p1 = pb4[tid * 2 + 1];
  float s = bf2f((u16)(wv.x & 0xffff)) * p0.x + bf2f((u16)(wv.x >> 16)) * p0.y +
            bf2f((u16)(wv.y & 0xffff)) * p0.z + bf2f((u16)(wv.y >> 16)) * p0.w +
            bf2f((u16)(wv.z & 0xffff)) * p1.x + bf2f((u16)(wv.z >> 16)) * p1.y +
            bf2f((u16)(wv.w & 0xffff)) * p1.z + bf2f((u16)(wv.w >> 16)) * p1.w;
  s += __shfl_xor(s, 1);  s += __shfl_xor(s, 2);
  s += __shfl_xor(s, 4);  s += __shfl_xor(s, 8);
  s += __shfl_xor(s, 16); s += __shfl_xor(s, 32);
  __shared__ float ls[4];
  if ((tid & 63) == 0) ls[tid >> 6] = s;
  __syncthreads();
  if (tid == 0) out[row] = ls[0] + ls[1] + ls[2] + ls[3] + base[row];
}

// ------------------------------------------------- flash attention (round-14 config, validated 145us)
__global__ __launch_bounds__(256) void attn_kernel(const u16* __restrict__ Q,
                                                   const u16* __restrict__ K,
                                                   const u16* __restrict__ Vt,
                                                   u16* __restrict__ Octx) {
  __shared__ __align__(16) u16 Ks[2][64 * 128];
  __shared__ __align__(16) u16 Vs[2][128 * 64];
  const int tid = threadIdx.x, wave = tid >> 6, lane = tid & 63;
  const int bid = blockIdx.x;
  const int qb = bid & 15, bh = bid >> 4, b = bh >> 4, h = bh & 15;
  const int q0 = qb << 7;
  const int l31 = lane & 31, hi = lane >> 5;
  const float Cs = 0.08838834764831845f * 1.4426950408889634f;  // 1/sqrt(128)*log2(e)

  const u16* Qp = Q + ((size_t)(b * LQ_ + q0 + wave * 32 + l31)) * E_ + h * DH_;
  const u16* Kp = K + ((size_t)(b * LKV_)) * E_ + h * DH_;
  const u16* Vp = Vt + (size_t)bh * DH_ * LKV_;

  const int kl_row = lane >> 4, kl_g = lane & 15;  // K stage: 4 rows of 256B
  const int vl_row = lane >> 3, vl_g = lane & 7;   // V stage: 8 rows of 128B

  // Q B-frags: col=q=l31, k=dh=c*16+hi*8+j; prescaled by Cs.
  bf16x8 qf[8];
#pragma unroll
  for (int c = 0; c < 8; ++c) {
    bf16x8 raw = *(const bf16x8*)&Qp[c * 16 + hi * 8];
#pragma unroll
    for (int j = 0; j < 8; ++j) qf[c][j] = (__bf16)((float)raw[j] * Cs);
  }

  // all-ones B-fragment for the row-sum MFMA
  bf16x8 VONES;
#pragma unroll
  for (int j = 0; j < 8; ++j) VONES[j] = (__bf16)1.0f;
  // loop-invariant zero C-operand (kills per-tile st zero-init movs)
  f32x16 FZERO = {};

  f32x16 o[4];
#pragma unroll
  for (int d = 0; d < 4; ++d)
#pragma unroll
    for (int r = 0; r < 16; ++r) o[d][r] = 0.f;
  f32x16 ol = {};  // row-sums accumulator (same C-layout as o)

  // stage kv-tile (8 global_load_lds) into buffer `buf`
  auto STAGE = [&](int kv0, int buf) {
#pragma unroll
    for (int j = 0; j < 4; ++j) {
      int cc = wave * 4 + j;
      int krow = cc * 4 + kl_row;
      GLDS(Kp + (size_t)(kv0 + krow) * E_ + ((kl_g ^ (krow & 15)) << 3), &Ks[buf][cc * 512]);
      int vrow = cc * 8 + vl_row;
      GLDS(Vp + (size_t)vrow * LKV_ + kv0 + ((vl_g ^ (vrow & 7)) << 3), &Vs[buf][cc * 512]);
    }
  };

  const int NT = LKV_ / 64;
  STAGE(0, 0);

  for (int t = 0; t < NT; ++t) {
    const int cur = t & 1;
    if (t + 1 < NT) {
      STAGE((t + 1) * 64, cur ^ 1);  // buf cur^1 released by end-barrier of t-1
      asm volatile("s_waitcnt vmcnt(8)" ::: "memory");  // own tile-t loads done
    } else {
      asm volatile("s_waitcnt vmcnt(0)" ::: "memory");
    }
    BARRIER();  // all waves' tile-t loads visible

    const u16* ks = Ks[cur];
    const u16* vs = Vs[cur];

    // S^T[kv][q]: A = K rows (kv = n*32 + l31, k = dh), B = Q. c=0 peeled w/ FZERO.
    f32x16 st[2];
#pragma unroll
    for (int n = 0; n < 2; ++n) {
      int row = n * 32 + l31;
      bf16x8 kf = *(const bf16x8*)&ks[row * 128 + ((hi ^ (row & 15)) << 3)];
      st[n] = __builtin_amdgcn_mfma_f32_32x32x16_bf16(kf, qf[0], FZERO, 0, 0, 0);
    }
#pragma unroll
    for (int c = 1; c < 8; ++c) {
#pragma unroll
      for (int n = 0; n < 2; ++n) {
        int row = n * 32 + l31;
        bf16x8 kf = *(const bf16x8*)&ks[row * 128 + (((c * 2 + hi) ^ (row & 15)) << 3)];
        st[n] = __builtin_amdgcn_mfma_f32_32x32x16_bf16(kf, qf[c], st[n], 0, 0, 0);
      }
    }

    // P = exp2(S') via raw v_exp_f32, pack PV A-frags in-register.
    unsigned AF[4][4];
#pragma unroll
    for (int n = 0; n < 2; ++n) {
      float pv[16];
#pragma unroll
      for (int r = 0; r < 16; ++r) pv[r] = fast_ex2(st[n][r]);
      unsigned a0 = cvtpk_bf16(pv[0], pv[1]),   a1 = cvtpk_bf16(pv[2], pv[3]);
      unsigned a2 = cvtpk_bf16(pv[4], pv[5]),   a3 = cvtpk_bf16(pv[6], pv[7]);
      unsigned b0 = cvtpk_bf16(pv[8], pv[9]),   b1 = cvtpk_bf16(pv[10], pv[11]);
      unsigned b2 = cvtpk_bf16(pv[12], pv[13]), b3 = cvtpk_bf16(pv[14], pv[15]);
      i32x2 r02 = __builtin_amdgcn_permlane32_swap((int)a0, (int)a2, false, false);
      i32x2 r13 = __builtin_amdgcn_permlane32_swap((int)a1, (int)a3, false, false);
      AF[n * 2][0] = (unsigned)r02[0]; AF[n * 2][1] = (unsigned)r13[0];
      AF[n * 2][2] = (unsigned)r02[1]; AF[n * 2][3] = (unsigned)r13[1];
      i32x2 s02 = __builtin_amdgcn_permlane32_swap((int)b0, (int)b2, false, false);
      i32x2 s13 = __builtin_amdgcn_permlane32_swap((int)b1, (int)b3, false, false);
      AF[n * 2 + 1][0] = (unsigned)s02[0]; AF[n * 2 + 1][1] = (unsigned)s13[0];
      AF[n * 2 + 1][2] = (unsigned)s02[1]; AF[n * 2 + 1][3] = (unsigned)s13[1];
    }

    // PV: A = P[q][kv-step], B = Vt[d][kv]; plus ones-B MFMA for row sums.
#pragma unroll
    for (int s = 0; s < 4; ++s) {
      union { unsigned u[4]; bf16x8 v; } pk;
      pk.u[0] = AF[s][0]; pk.u[1] = AF[s][1]; pk.u[2] = AF[s][2]; pk.u[3] = AF[s][3];
      bf16x8 pa = pk.v;
#pragma unroll
      for (int db = 0; db < 4; ++db) {
        int d = db * 32 + l31;
        bf16x8 vf = *(const bf16x8*)&vs[d * 64 + (((s * 2 + hi) ^ (d & 7)) << 3)];
        o[db] = __builtin_amdgcn_mfma_f32_32x32x16_bf16(pa, vf, o[db], 0, 0, 0);
      }
      ol = __builtin_amdgcn_mfma_f32_32x32x16_bf16(pa, VONES, ol, 0, 0, 0);
    }
    BARRIER();  // all waves done reading buf cur -> free for staging at t+1
  }

  // write ctx: li = 1/ol[r] (ol row layout == o row layout)
#pragma unroll
  for (int r = 0; r < 16; ++r) {
    int crow = (r & 3) + 8 * (r >> 2) + 4 * hi;
    float li = 1.0f / ol[r];
    size_t rb = ((size_t)(b * LQ_ + q0 + wave * 32 + crow)) * E_ + h * DH_ + l31;
#pragma unroll
    for (int db = 0; db < 4; ++db)
      Octx[rb + db * 32] = f2bf(o[db][r] * li);
  }
}

// ------------------------------------------------- RMSNorm (Gemma) + residual, bf16 input
__global__ __launch_bounds__(256) void rms_res_bf(const u16* __restrict__ x,
                                                  const float* __restrict__ w,
                                                  const float* __restrict__ qres,
                                                  float* __restrict__ out) {
  int row = blockIdx.x, tid = threadIdx.x;
  uint4 xv = ((const uint4*)(x + (size_t)row * E_))[tid];  // 8 bf16
  float xf[8];
  xf[0] = bf2f((u16)(xv.x & 0xffff)); xf[1] = bf2f((u16)(xv.x >> 16));
  xf[2] = bf2f((u16)(xv.y & 0xffff)); xf[3] = bf2f((u16)(xv.y >> 16));
  xf[4] = bf2f((u16)(xv.z & 0xffff)); xf[5] = bf2f((u16)(xv.z >> 16));
  xf[6] = bf2f((u16)(xv.w & 0xffff)); xf[7] = bf2f((u16)(xv.w >> 16));
  float ss = 0.f;
#pragma unroll
  for (int j = 0; j < 8; ++j) ss += xf[j] * xf[j];
  ss += __shfl_xor(ss, 1);  ss += __shfl_xor(ss, 2);
  ss += __shfl_xor(ss, 4);  ss += __shfl_xor(ss, 8);
  ss += __shfl_xor(ss, 16); ss += __shfl_xor(ss, 32);
  __shared__ float ls[4];
  if ((tid & 63) == 0) ls[tid >> 6] = ss;
  __syncthreads();
  float total = ls[0] + ls[1] + ls[2] + ls[3];
  float rs = rsqrtf(total * (1.0f / (float)E_) + 1e-6f);
  const float4* qr = (const float4*)(qres + (size_t)row * E_);
  const float4* wr4 = (const float4*)w;
  float4 q0 = qr[tid * 2], q1 = qr[tid * 2 + 1];
  float4 w0 = wr4[tid * 2], w1 = wr4[tid * 2 + 1];
  float4 o0, o1;
  o0.x = xf[0] * rs * (1.f + w0.x) + q0.x;
  o0.y = xf[1] * rs * (1.f + w0.y) + q0.y;
  o0.z = xf[2] * rs * (1.f + w0.z) + q0.z;
  o0.w = xf[3] * rs * (1.f + w0.w) + q0.w;
  o1.x = xf[4] * rs * (1.f + w1.x) + q1.x;
  o1.y = xf[5] * rs * (1.f + w1.y) + q1.y;
  o1.z = xf[6] * rs * (1.f + w1.z) + q1.z;
  o1.w = xf[7] * rs * (1.f + w1.w) + q1.w;
  float4* op = (float4*)(out + (size_t)row * E_);
  op[tid * 2] = o0;
  op[tid * 2 + 1] = o1;
}

// ------------------------------------------------- launcher
extern "C" void kernel_launch(void* const* d_in, const int* in_sizes, int n_in,
                              void* d_out, int out_size, void* d_ws, size_t ws_size,
                              hipStream_t stream) {
  const float* query = (const float*)d_in[0];
  const float* aug   = (const float*)d_in[1];
  // d_in[2] = aug_mask: unused by the reference forward
  const float* projw = (const float*)d_in[3];
  const float* projb = (const float*)d_in[4];
  const float* ipw   = (const float*)d_in[5];
  const float* ipb   = (const float*)d_in[6];
  const float* opw   = (const float*)d_in[7];
  const float* opb   = (const float*)d_in[8];
  const float* rmsw  = (const float*)d_in[9];

  char* ws = (char*)d_ws;
  size_t off = 0;
  auto alloc = [&](size_t bytes) {
    void* p = ws + off;
    off += (bytes + 1023) & ~(size_t)1023;
    return p;
  };
  // ws footprint unchanged from round 18 (256.2MB). Fusion scratch lives in
  // kv_bf's region; vt lives in v_bf's region (v GEMM scatters directly).
  u16* query_bf = (u16*)alloc((size_t)B_ * LQ_ * E_ * 2);        // 33.6MB
  u16* aug_bf   = (u16*)alloc((size_t)B_ * LKV_ * AUG_ * 2);     // 16.8MB
  u16* projw_bf = (u16*)alloc((size_t)E_ * AUG_ * 2);            //  4.2MB
  u16* w_bf     = (u16*)alloc((size_t)3 * E_ * E_ * 2);          // 25.2MB
  u16* outw_bf  = (u16*)alloc((size_t)E_ * E_ * 2);              //  8.4MB
  u16* kv_bf    = (u16*)alloc((size_t)B_ * LKV_ * E_ * 2);       // 33.6MB (fusion scratch)
  u16* q_bf     = (u16*)alloc((size_t)B_ * LQ_ * E_ * 2);
  u16* k_bf     = (u16*)alloc((size_t)B_ * LKV_ * E_ * 2);
  u16* v_bf     = (u16*)alloc((size_t)B_ * LKV_ * E_ * 2);       // holds vt
  u16* ctx_bf   = (u16*)alloc((size_t)B_ * LQ_ * E_ * 2);
  u16* attn_out = query_bf;            // alias: region 0 all dead by then (bf16)
  // fusion scratch carved from kv_bf (12MiB + 16KB < 32MiB):
  u16* projwT = kv_bf;                                       // AUG*E u16 = 4MiB
  u16* wkv_f  = kv_bf + (size_t)AUG_ * E_;                   // 2E*AUG u16 = 8MiB
  float* bkv  = (float*)(kv_bf + (size_t)AUG_ * E_ + (size_t)2 * E_ * AUG_);  // 16KB
  u16* vt_bf = v_bf;                   // v GEMM writes vt here directly
  (void)in_sizes; (void)n_in; (void)ws_size;

  const int M = B_ * LQ_;  // 8192

  // fused cast of all 5 f32 tensors -> bf16 (single launch)
  const int n8_q  = (int)((size_t)M * E_ / 8);
  const int n8_a  = (int)((size_t)M * AUG_ / 8);
  const int n8_pw = (int)((size_t)E_ * AUG_ / 8);
  const int n8_iw = (int)((size_t)3 * E_ * E_ / 8);
  const int n8_ow = (int)((size_t)E_ * E_ / 8);
  const int cc0 = n8_q, cc1 = cc0 + n8_a, cc2 = cc1 + n8_pw, cc3 = cc2 + n8_iw,
            cc4 = cc3 + n8_ow;
  cast5<<<2048, 256, 0, stream>>>(query, query_bf, cc0,
                                  aug, aug_bf, cc1,
                                  projw, projw_bf, cc2,
                                  ipw, w_bf, cc3,
                                  opw, outw_bf, cc4);

  // projwT[AUG,E] = projw^T
  transpose_w<<<dim3(AUG_ / 64, E_ / 64), 256, 0, stream>>>(projw_bf, projwT, E_, AUG_);
  // Wkv[2E, AUG] = [wk; wv] @ projw  (weight-space fusion)
  gemm_bt2<0><<<dim3(AUG_ / 256, (2 * E_) / 256), 512, 0, stream>>>(
      w_bf + (size_t)E_ * E_, projwT, nullptr, wkv_f, AUG_, E_);
  // bkv[2E] = [wk; wv] @ projb + ipb[E..3E]
  gemv_bias<<<2 * E_, 256, 0, stream>>>(w_bf + (size_t)E_ * E_, projb, ipb + E_, bkv, E_);

  // q = query @ wq^T + bq
  gemm_bt2<0><<<dim3(E_ / 256, M / 256), 512, 0, stream>>>(query_bf, w_bf, ipb, q_bf, E_, E_);
  // k = aug @ Wk_f^T + bk'   (K = AUG = 1024)
  gemm_bt2<0><<<dim3(E_ / 256, M / 256), 512, 0, stream>>>(aug_bf, wkv_f, bkv, k_bf, E_, AUG_);
  // vt[b,h,d,kv] = (aug @ Wv_f^T + bv')^T  -- scatter epilogue, no transpose pass
  gemm_bt2<2><<<dim3(E_ / 256, M / 256), 512, 0, stream>>>(
      aug_bf, wkv_f + (size_t)E_ * AUG_, bkv + E_, vt_bf, E_, AUG_);
  // attention -> ctx  (QBLK=128 per block)
  attn_kernel<<<B_ * H_ * (LQ_ / 128), 256, 0, stream>>>(q_bf, k_bf, vt_bf, ctx_bf);
  // attn_out = ctx @ out_proj^T + b (bf16)
  gemm_bt2<0><<<dim3(E_ / 256, M / 256), 512, 0, stream>>>(ctx_bf, outw_bf, opb, attn_out, E_, E_);
  // out = RMSNorm(attn_out)*(1+w) + query
  rms_res_bf<<<M, 256, 0, stream>>>(attn_out, rmsw, query, (float*)d_out);
}

// Round 24
// 464.550 us; speedup vs baseline: 1.0638x; 1.0077x over previous
//
#include <hip/hip_runtime.h>
#include <hip/hip_bf16.h>
#include <stdint.h>

// Problem constants
#define B_   4
#define LQ_  2048
#define LKV_ 2048
#define E_   2048
#define AUG_ 1024
#define H_   16
#define DH_  128

typedef unsigned short u16;
typedef __bf16 bf16x8 __attribute__((ext_vector_type(8)));
typedef float f32x4 __attribute__((ext_vector_type(4)));
typedef float f32x16 __attribute__((ext_vector_type(16)));
typedef int i32x2 __attribute__((ext_vector_type(2)));

__device__ __forceinline__ u16 f2bf(float f) {
  union { float f; unsigned u; } v; v.f = f;
  unsigned r = v.u + 0x7fffu + ((v.u >> 16) & 1u);
  return (u16)(r >> 16);
}
__device__ __forceinline__ unsigned pk2(float a, float b) {
  return (unsigned)f2bf(a) | ((unsigned)f2bf(b) << 16);
}
__device__ __forceinline__ float bf2f(u16 u) {
  union { unsigned u; float f; } v; v.u = (unsigned)u << 16; return v.f;
}
// v_cvt_pk_bf16_f32: lo -> bits[15:0], hi -> bits[31:16] (no builtin on gfx950)
__device__ __forceinline__ unsigned cvtpk_bf16(float lo, float hi) {
  unsigned r;
  asm("v_cvt_pk_bf16_f32 %0, %1, %2" : "=v"(r) : "v"(lo), "v"(hi));
  return r;
}
// raw v_exp_f32 (2^x): skips libm's denormal/range fixup (~15 VALU ops/call).
__device__ __forceinline__ float fast_ex2(float x) {
  float r;
  asm("v_exp_f32 %0, %1" : "=v"(r) : "v"(x));
  return r;
}

// async global->LDS, 16B per lane. LDS dest must be wave-uniform; HW adds lane*16.
#define GLDS(gsrc, ldst)                                                        \
  __builtin_amdgcn_global_load_lds(                                             \
      (__attribute__((address_space(1))) void*)(uintptr_t)(gsrc),               \
      (__attribute__((address_space(3))) void*)(unsigned)(uintptr_t)(ldst),     \
      16, 0, 0)

// raw workgroup barrier with compiler memory-motion fences (NO vmcnt drain)
#define BARRIER()                                   \
  do {                                              \
    asm volatile("" ::: "memory");                  \
    __builtin_amdgcn_s_barrier();                   \
    asm volatile("" ::: "memory");                  \
  } while (0)

// ------------------------------------------- fused cast f32->bf16 (5 tensors)
__global__ __launch_bounds__(256) void cast5(const float* __restrict__ p0, u16* __restrict__ o0, int c0,
                                             const float* __restrict__ p1, u16* __restrict__ o1, int c1,
                                             const float* __restrict__ p2, u16* __restrict__ o2, int c2,
                                             const float* __restrict__ p3, u16* __restrict__ o3, int c3,
                                             const float* __restrict__ p4, u16* __restrict__ o4, int c4) {
  int stride = gridDim.x * blockDim.x;
  for (int i = blockIdx.x * blockDim.x + threadIdx.x; i < c4; i += stride) {
    const float* in; u16* out; int j;
    if (i < c0)      { in = p0; out = o0; j = i; }
    else if (i < c1) { in = p1; out = o1; j = i - c0; }
    else if (i < c2) { in = p2; out = o2; j = i - c1; }
    else if (i < c3) { in = p3; out = o3; j = i - c2; }
    else             { in = p4; out = o4; j = i - c3; }
    const float4* p = (const float4*)in + (size_t)j * 2;
    float4 a = p[0], b = p[1];
    uint4 o;
    o.x = pk2(a.x, a.y); o.y = pk2(a.z, a.w);
    o.z = pk2(b.x, b.y); o.w = pk2(b.z, b.w);
    ((uint4*)out)[j] = o;
  }
}

// ------------------------------------------------- GEMM: C[M,N] = A[M,K]*W[N,K]^T + bias
// 256x256 tile, 8 waves (2M x 4N), BK=32, ring-of-3 K-tile LDS pipeline (96 KiB).
// SINGLE barrier/tile (validated round 18). vmcnt(4) counted, never 0 mid-loop.
// OUTMODE: 0 = bf16 row-major C[M][N];
//          2 = bf16 scatter into vt[b,h,d,kv];
//          3 = merged k+v: n0<2048 -> k row-major (stride 2048) into Cp,
//              n0>=2048 -> vt scatter (col-2048) into Cp2. 2048 boundary is
//              256-aligned -> per-block uniform branch.
template <int OUTMODE>
__global__ __launch_bounds__(512, 2) void gemm_bt2(const u16* __restrict__ A,
                                                   const u16* __restrict__ W,
                                                   const float* __restrict__ bias,
                                                   void* __restrict__ Cp,
                                                   void* __restrict__ Cp2,
                                                   int N, int K) {
  __shared__ __align__(16) u16 As[3][256 * 32];
  __shared__ __align__(16) u16 Bs[3][256 * 32];
  const int tid = threadIdx.x;
  const int wave = tid >> 6, lane = tid & 63;
  const int wr = wave >> 2, wc = wave & 3;          // 2 x 4 wave grid
  const int g = lane >> 4, r16 = lane & 15;
  const int m0 = blockIdx.y << 8, n0 = blockIdx.x << 8;

  size_t gA[2], gB[2];
  int ldst[2];
#pragma unroll
  for (int i = 0; i < 2; ++i) {
    int c = tid + i * 512;
    int s = c >> 6, w = c & 63;
    int wp = w ^ (((w >> 5) & 1) << 1);
    int grow = s * 16 + (wp >> 2);
    int gcol = (wp & 3) * 8;
    gA[i] = (size_t)(m0 + grow) * K + gcol;
    gB[i] = (size_t)(n0 + grow) * K + gcol;
    ldst[i] = c * 8;  // u16 elements (16B chunks)
  }
  const int aoff = r16 * 32 + ((g * 8) ^ ((r16 & 8) ? 16 : 0));

  f32x4 acc[8][4];
#pragma unroll
  for (int m = 0; m < 8; ++m)
#pragma unroll
    for (int n = 0; n < 4; ++n) acc[m][n] = (f32x4){0.f, 0.f, 0.f, 0.f};

  const int NT = K >> 5;
#pragma unroll
  for (int i = 0; i < 2; ++i) GLDS(A + gA[i], &As[0][ldst[i]]);
#pragma unroll
  for (int i = 0; i < 2; ++i) GLDS(W + gB[i], &Bs[0][ldst[i]]);
#pragma unroll
  for (int i = 0; i < 2; ++i) GLDS(A + gA[i] + 32, &As[1][ldst[i]]);
#pragma unroll
  for (int i = 0; i < 2; ++i) GLDS(W + gB[i] + 32, &Bs[1][ldst[i]]);

  int cur = 0;
  for (int t = 0; t < NT; ++t) {
    if (t + 1 < NT)
      asm volatile("s_waitcnt vmcnt(4)" ::: "memory");
    else
      asm volatile("s_waitcnt vmcnt(0)" ::: "memory");
    BARRIER();  // top barrier: tile t visible; also fences slot (t+2)%3 reuse

    const u16* as = As[cur];
    const u16* bs = Bs[cur];
    int nxt = cur + 2; if (nxt >= 3) nxt -= 3;

    bf16x8 bfr[4], af[4];
#pragma unroll
    for (int n = 0; n < 4; ++n)
      bfr[n] = *(const bf16x8*)&bs[wc * 2048 + n * 512 + aoff];
#pragma unroll
    for (int m = 0; m < 4; ++m)
      af[m] = *(const bf16x8*)&as[wr * 4096 + m * 512 + aoff];
    if (t + 2 < NT) {
      size_t k0 = (size_t)(t + 2) * 32;
#pragma unroll
      for (int i = 0; i < 2; ++i) GLDS(A + gA[i] + k0, &As[nxt][ldst[i]]);
    }
    __builtin_amdgcn_s_setprio(1);
#pragma unroll
    for (int m = 0; m < 4; ++m)
#pragma unroll
      for (int n = 0; n < 4; ++n)
        acc[m][n] = __builtin_amdgcn_mfma_f32_16x16x32_bf16(af[m], bfr[n], acc[m][n], 0, 0, 0);
    __builtin_amdgcn_s_setprio(0);

    bf16x8 af2[4];
#pragma unroll
    for (int m = 0; m < 4; ++m)
      af2[m] = *(const bf16x8*)&as[wr * 4096 + (m + 4) * 512 + aoff];
    if (t + 2 < NT) {
      size_t k0 = (size_t)(t + 2) * 32;
#pragma unroll
      for (int i = 0; i < 2; ++i) GLDS(W + gB[i] + k0, &Bs[nxt][ldst[i]]);
    }
    __builtin_amdgcn_s_setprio(1);
#pragma unroll
    for (int m = 0; m < 4; ++m)
#pragma unroll
      for (int n = 0; n < 4; ++n)
        acc[m + 4][n] = __builtin_amdgcn_mfma_f32_16x16x32_bf16(af2[m], bfr[n], acc[m + 4][n], 0, 0, 0);
    __builtin_amdgcn_s_setprio(0);

    cur = cur + 1; if (cur >= 3) cur -= 3;
  }

  float bv[4];
#pragma unroll
  for (int n = 0; n < 4; ++n)
    bv[n] = bias ? bias[n0 + wc * 64 + n * 16 + r16] : 0.f;
#pragma unroll
  for (int m = 0; m < 8; ++m) {
    int row = m0 + wr * 128 + m * 16 + g * 4;
#pragma unroll
    for (int n = 0; n < 4; ++n) {
      int col = n0 + wc * 64 + n * 16 + r16;
      if (OUTMODE == 2 || (OUTMODE == 3 && n0 >= 2048)) {
        int colp = (OUTMODE == 3) ? (col - 2048) : col;
        void* dst = (OUTMODE == 3) ? Cp2 : Cp;
        // vt[((b*16+h)*128+d)*2048 + kv], b=row>>11, kv=row&2047, h=colp>>7, d=colp&127
        size_t base = (((size_t)((row >> 11) * 16 + (colp >> 7)) * 128 + (colp & 127)) << 11) + (row & 2047);
        uint2 o2;
        o2.x = pk2(acc[m][n][0] + bv[n], acc[m][n][1] + bv[n]);
        o2.y = pk2(acc[m][n][2] + bv[n], acc[m][n][3] + bv[n]);
        *(uint2*)&((u16*)dst)[base] = o2;
      } else {
        int stride = (OUTMODE == 3) ? 2048 : N;
#pragma unroll
        for (int r = 0; r < 4; ++r) {
          float v = acc[m][n][r] + bv[n];
          ((u16*)Cp)[(size_t)(row + r) * stride + col] = f2bf(v);
        }
      }
    }
  }
}

// ------------------------------------------------- generic bf16 transpose: in[R][C] -> out[C][R]
__global__ __launch_bounds__(256) void transpose_w(const u16* __restrict__ in,
                                                   u16* __restrict__ out,
                                                   int R, int C) {
  __shared__ __align__(16) u16 t[64][72];
  int tid = threadIdx.x;
  int c0 = blockIdx.x << 6, r0 = blockIdx.y << 6;
  int gr = tid & 7, rw = tid >> 3;  // rw 0..31
#pragma unroll
  for (int p = 0; p < 2; ++p) {
    int row = rw + p * 32;
    uint4 x = *(const uint4*)&in[(size_t)(r0 + row) * C + c0 + gr * 8];
    *(uint4*)&t[row][gr * 8] = x;
  }
  __syncthreads();
#pragma unroll
  for (int p = 0; p < 2; ++p) {
    int d = rw + p * 32;  // col-local
    u16 tmp[8];
#pragma unroll
    for (int j = 0; j < 8; ++j) tmp[j] = t[gr * 8 + j][d];
    uint4 o;
    o.x = (unsigned)tmp[0] | ((unsigned)tmp[1] << 16);
    o.y = (unsigned)tmp[2] | ((unsigned)tmp[3] << 16);
    o.z = (unsigned)tmp[4] | ((unsigned)tmp[5] << 16);
    o.w = (unsigned)tmp[6] | ((unsigned)tmp[7] << 16);
    *(uint4*)&out[(size_t)(c0 + d) * R + r0 + gr * 8] = o;
  }
}

// ------------------------------------------------- bias GEMV: out[i] = W[i,:] . pb + base[i]
__global__ __launch_bounds__(256) void gemv_bias(const u16* __restrict__ W,
                                                 const float* __restrict__ pb,
                                                 const float* __restrict__ base,
                                                 float* __restrict__ out, int K) {
  int row = blockIdx.x, tid = threadIdx.x;
  uint4 wv = ((const uint4*)(W + (size_t)row * K))[tid];  // 8 bf16
  const float4* pb4 = (const float4*)pb;
  float4 p0 = pb4[tid * 2], p1 = pb4[tid * 2 + 1];
  float s = bf2f((u16)(wv.x & 0xffff)) * p0.x + bf2f((u16)(wv.x >> 16)) * p0.y +
            bf2f((u16)(wv.y & 0xffff)) * p0.z + bf2f((u16)(wv.y >> 16)) * p0.w +
            bf2f((u16)(wv.z & 0xffff)) * p1.x + bf2f((u16)(wv.z >> 16)) * p1.y +
            bf2f((u16)(wv.w & 0xffff)) * p1.z + bf2f((u16)(wv.w >> 16)) * p1.w;
  s += __shfl_xor(s, 1);  s += __shfl_xor(s, 2);
  s += __shfl_xor(s, 4);  s += __shfl_xor(s, 8);
  s += __shfl_xor(s, 16); s += __shfl_xor(s, 32);
  __shared__ float ls[4];
  if ((tid & 63) == 0) ls[tid >> 6] = s;
  __syncthreads();
  if (tid == 0) out[row] = ls[0] + ls[1] + ls[2] + ls[3] + base[row];
}

// ------------------------------------------------- flash attention (round-14 config, validated 145us)
__global__ __launch_bounds__(256) void attn_kernel(const u16* __restrict__ Q,
                                                   const u16* __restrict__ K,
                                                   const u16* __restrict__ Vt,
                                                   u16* __restrict__ Octx) {
  __shared__ __align__(16) u16 Ks[2][64 * 128];
  __shared__ __align__(16) u16 Vs[2][128 * 64];
  const int tid = threadIdx.x, wave = tid >> 6, lane = tid & 63;
  const int bid = blockIdx.x;
  const int qb = bid & 15, bh = bid >> 4, b = bh >> 4, h = bh & 15;
  const int q0 = qb << 7;
  const int l31 = lane & 31, hi = lane >> 5;
  const float Cs = 0.08838834764831845f * 1.4426950408889634f;  // 1/sqrt(128)*log2(e)

  const u16* Qp = Q + ((size_t)(b * LQ_ + q0 + wave * 32 + l31)) * E_ + h * DH_;
  const u16* Kp = K + ((size_t)(b * LKV_)) * E_ + h * DH_;
  const u16* Vp = Vt + (size_t)bh * DH_ * LKV_;

  const int kl_row = lane >> 4, kl_g = lane & 15;  // K stage: 4 rows of 256B
  const int vl_row = lane >> 3, vl_g = lane & 7;   // V stage: 8 rows of 128B

  // Q B-frags: col=q=l31, k=dh=c*16+hi*8+j; prescaled by Cs.
  bf16x8 qf[8];
#pragma unroll
  for (int c = 0; c < 8; ++c) {
    bf16x8 raw = *(const bf16x8*)&Qp[c * 16 + hi * 8];
#pragma unroll
    for (int j = 0; j < 8; ++j) qf[c][j] = (__bf16)((float)raw[j] * Cs);
  }

  // all-ones B-fragment for the row-sum MFMA
  bf16x8 VONES;
#pragma unroll
  for (int j = 0; j < 8; ++j) VONES[j] = (__bf16)1.0f;
  // loop-invariant zero C-operand (kills per-tile st zero-init movs)
  f32x16 FZERO = {};

  f32x16 o[4];
#pragma unroll
  for (int d = 0; d < 4; ++d)
#pragma unroll
    for (int r = 0; r < 16; ++r) o[d][r] = 0.f;
  f32x16 ol = {};  // row-sums accumulator (same C-layout as o)

  // stage kv-tile (8 global_load_lds) into buffer `buf`
  auto STAGE = [&](int kv0, int buf) {
#pragma unroll
    for (int j = 0; j < 4; ++j) {
      int cc = wave * 4 + j;
      int krow = cc * 4 + kl_row;
      GLDS(Kp + (size_t)(kv0 + krow) * E_ + ((kl_g ^ (krow & 15)) << 3), &Ks[buf][cc * 512]);
      int vrow = cc * 8 + vl_row;
      GLDS(Vp + (size_t)vrow * LKV_ + kv0 + ((vl_g ^ (vrow & 7)) << 3), &Vs[buf][cc * 512]);
    }
  };

  const int NT = LKV_ / 64;
  STAGE(0, 0);

  for (int t = 0; t < NT; ++t) {
    const int cur = t & 1;
    if (t + 1 < NT) {
      STAGE((t + 1) * 64, cur ^ 1);  // buf cur^1 released by end-barrier of t-1
      asm volatile("s_waitcnt vmcnt(8)" ::: "memory");  // own tile-t loads done
    } else {
      asm volatile("s_waitcnt vmcnt(0)" ::: "memory");
    }
    BARRIER();  // all waves' tile-t loads visible

    const u16* ks = Ks[cur];
    const u16* vs = Vs[cur];

    // S^T[kv][q]: A = K rows (kv = n*32 + l31, k = dh), B = Q. c=0 peeled w/ FZERO.
    f32x16 st[2];
#pragma unroll
    for (int n = 0; n < 2; ++n) {
      int row = n * 32 + l31;
      bf16x8 kf = *(const bf16x8*)&ks[row * 128 + ((hi ^ (row & 15)) << 3)];
      st[n] = __builtin_amdgcn_mfma_f32_32x32x16_bf16(kf, qf[0], FZERO, 0, 0, 0);
    }
#pragma unroll
    for (int c = 1; c < 8; ++c) {
#pragma unroll
      for (int n = 0; n < 2; ++n) {
        int row = n * 32 + l31;
        bf16x8 kf = *(const bf16x8*)&ks[row * 128 + (((c * 2 + hi) ^ (row & 15)) << 3)];
        st[n] = __builtin_amdgcn_mfma_f32_32x32x16_bf16(kf, qf[c], st[n], 0, 0, 0);
      }
    }

    // P = exp2(S') via raw v_exp_f32, pack PV A-frags in-register.
    unsigned AF[4][4];
#pragma unroll
    for (int n = 0; n < 2; ++n) {
      float pv[16];
#pragma unroll
      for (int r = 0; r < 16; ++r) pv[r] = fast_ex2(st[n][r]);
      unsigned a0 = cvtpk_bf16(pv[0], pv[1]),   a1 = cvtpk_bf16(pv[2], pv[3]);
      unsigned a2 = cvtpk_bf16(pv[4], pv[5]),   a3 = cvtpk_bf16(pv[6], pv[7]);
      unsigned b0 = cvtpk_bf16(pv[8], pv[9]),   b1 = cvtpk_bf16(pv[10], pv[11]);
      unsigned b2 = cvtpk_bf16(pv[12], pv[13]), b3 = cvtpk_bf16(pv[14], pv[15]);
      i32x2 r02 = __builtin_amdgcn_permlane32_swap((int)a0, (int)a2, false, false);
      i32x2 r13 = __builtin_amdgcn_permlane32_swap((int)a1, (int)a3, false, false);
      AF[n * 2][0] = (unsigned)r02[0]; AF[n * 2][1] = (unsigned)r13[0];
      AF[n * 2][2] = (unsigned)r02[1]; AF[n * 2][3] = (unsigned)r13[1];
      i32x2 s02 = __builtin_amdgcn_permlane32_swap((int)b0, (int)b2, false, false);
      i32x2 s13 = __builtin_amdgcn_permlane32_swap((int)b1, (int)b3, false, false);
      AF[n * 2 + 1][0] = (unsigned)s02[0]; AF[n * 2 + 1][1] = (unsigned)s13[0];
      AF[n * 2 + 1][2] = (unsigned)s02[1]; AF[n * 2 + 1][3] = (unsigned)s13[1];
    }

    // PV: A = P[q][kv-step], B = Vt[d][kv]; plus ones-B MFMA for row sums.
#pragma unroll
    for (int s = 0; s < 4; ++s) {
      union { unsigned u[4]; bf16x8 v; } pk;
      pk.u[0] = AF[s][0]; pk.u[1] = AF[s][1]; pk.u[2] = AF[s][2]; pk.u[3] = AF[s][3];
      bf16x8 pa = pk.v;
#pragma unroll
      for (int db = 0; db < 4; ++db) {
        int d = db * 32 + l31;
        bf16x8 vf = *(const bf16x8*)&vs[d * 64 + (((s * 2 + hi) ^ (d & 7)) << 3)];
        o[db] = __builtin_amdgcn_mfma_f32_32x32x16_bf16(pa, vf, o[db], 0, 0, 0);
      }
      ol = __builtin_amdgcn_mfma_f32_32x32x16_bf16(pa, VONES, ol, 0, 0, 0);
    }
    BARRIER();  // all waves done reading buf cur -> free for staging at t+1
  }

  // write ctx: li = 1/ol[r] (ol row layout == o row layout)
#pragma unroll
  for (int r = 0; r < 16; ++r) {
    int crow = (r & 3) + 8 * (r >> 2) + 4 * hi;
    float li = 1.0f / ol[r];
    size_t rb = ((size_t)(b * LQ_ + q0 + wave * 32 + crow)) * E_ + h * DH_ + l31;
#pragma unroll
    for (int db = 0; db < 4; ++db)
      Octx[rb + db * 32] = f2bf(o[db][r] * li);
  }
}

// ------------------------------------------------- RMSNorm (Gemma) + residual, bf16 input
__global__ __launch_bounds__(256) void rms_res_bf(const u16* __restrict__ x,
                                                  const float* __restrict__ w,
                                                  const float* __restrict__ qres,
                                                  float* __restrict__ out) {
  int row = blockIdx.x, tid = threadIdx.x;
  uint4 xv = ((const uint4*)(x + (size_t)row * E_))[tid];  // 8 bf16
  float xf[8];
  xf[0] = bf2f((u16)(xv.x & 0xffff)); xf[1] = bf2f((u16)(xv.x >> 16));
  xf[2] = bf2f((u16)(xv.y & 0xffff)); xf[3] = bf2f((u16)(xv.y >> 16));
  xf[4] = bf2f((u16)(xv.z & 0xffff)); xf[5] = bf2f((u16)(xv.z >> 16));
  xf[6] = bf2f((u16)(xv.w & 0xffff)); xf[7] = bf2f((u16)(xv.w >> 16));
  float ss = 0.f;
#pragma unroll
  for (int j = 0; j < 8; ++j) ss += xf[j] * xf[j];
  ss += __shfl_xor(ss, 1);  ss += __shfl_xor(ss, 2);
  ss += __shfl_xor(ss, 4);  ss += __shfl_xor(ss, 8);
  ss += __shfl_xor(ss, 16); ss += __shfl_xor(ss, 32);
  __shared__ float ls[4];
  if ((tid & 63) == 0) ls[tid >> 6] = ss;
  __syncthreads();
  float total = ls[0] + ls[1] + ls[2] + ls[3];
  float rs = rsqrtf(total * (1.0f / (float)E_) + 1e-6f);
  const float4* qr = (const float4*)(qres + (size_t)row * E_);
  const float4* wr4 = (const float4*)w;
  float4 q0 = qr[tid * 2], q1 = qr[tid * 2 + 1];
  float4 w0 = wr4[tid * 2], w1 = wr4[tid * 2 + 1];
  float4 o0, o1;
  o0.x = xf[0] * rs * (1.f + w0.x) + q0.x;
  o0.y = xf[1] * rs * (1.f + w0.y) + q0.y;
  o0.z = xf[2] * rs * (1.f + w0.z) + q0.z;
  o0.w = xf[3] * rs * (1.f + w0.w) + q0.w;
  o1.x = xf[4] * rs * (1.f + w1.x) + q1.x;
  o1.y = xf[5] * rs * (1.f + w1.y) + q1.y;
  o1.z = xf[6] * rs * (1.f + w1.z) + q1.z;
  o1.w = xf[7] * rs * (1.f + w1.w) + q1.w;
  float4* op = (float4*)(out + (size_t)row * E_);
  op[tid * 2] = o0;
  op[tid * 2 + 1] = o1;
}

// ------------------------------------------------- launcher
extern "C" void kernel_launch(void* const* d_in, const int* in_sizes, int n_in,
                              void* d_out, int out_size, void* d_ws, size_t ws_size,
                              hipStream_t stream) {
  const float* query = (const float*)d_in[0];
  const float* aug   = (const float*)d_in[1];
  // d_in[2] = aug_mask: unused by the reference forward
  const float* projw = (const float*)d_in[3];
  const float* projb = (const float*)d_in[4];
  const float* ipw   = (const float*)d_in[5];
  const float* ipb   = (const float*)d_in[6];
  const float* opw   = (const float*)d_in[7];
  const float* opb   = (const float*)d_in[8];
  const float* rmsw  = (const float*)d_in[9];

  char* ws = (char*)d_ws;
  size_t off = 0;
  auto alloc = [&](size_t bytes) {
    void* p = ws + off;
    off += (bytes + 1023) & ~(size_t)1023;
    return p;
  };
  // ws footprint unchanged from round 18 (256.2MB). Fusion scratch lives in
  // kv_bf's region; vt lives in v_bf's region.
  u16* query_bf = (u16*)alloc((size_t)B_ * LQ_ * E_ * 2);        // 33.6MB
  u16* aug_bf   = (u16*)alloc((size_t)B_ * LKV_ * AUG_ * 2);     // 16.8MB
  u16* projw_bf = (u16*)alloc((size_t)E_ * AUG_ * 2);            //  4.2MB
  u16* w_bf     = (u16*)alloc((size_t)3 * E_ * E_ * 2);          // 25.2MB
  u16* outw_bf  = (u16*)alloc((size_t)E_ * E_ * 2);              //  8.4MB
  u16* kv_bf    = (u16*)alloc((size_t)B_ * LKV_ * E_ * 2);       // 33.6MB (fusion scratch)
  u16* q_bf     = (u16*)alloc((size_t)B_ * LQ_ * E_ * 2);
  u16* k_bf     = (u16*)alloc((size_t)B_ * LKV_ * E_ * 2);
  u16* v_bf     = (u16*)alloc((size_t)B_ * LKV_ * E_ * 2);       // holds vt
  u16* ctx_bf   = (u16*)alloc((size_t)B_ * LQ_ * E_ * 2);
  u16* attn_out = query_bf;            // alias: region 0 all dead by then (bf16)
  // fusion scratch carved from kv_bf (12MiB + 16KB < 32MiB):
  u16* projwT = kv_bf;                                       // AUG*E u16 = 4MiB
  u16* wkv_f  = kv_bf + (size_t)AUG_ * E_;                   // 2E*AUG u16 = 8MiB
  float* bkv  = (float*)(kv_bf + (size_t)AUG_ * E_ + (size_t)2 * E_ * AUG_);  // 16KB
  u16* vt_bf = v_bf;                   // merged GEMM scatters vt here
  (void)in_sizes; (void)n_in; (void)ws_size;

  const int M = B_ * LQ_;  // 8192

  // fused cast of all 5 f32 tensors -> bf16 (single launch)
  const int n8_q  = (int)((size_t)M * E_ / 8);
  const int n8_a  = (int)((size_t)M * AUG_ / 8);
  const int n8_pw = (int)((size_t)E_ * AUG_ / 8);
  const int n8_iw = (int)((size_t)3 * E_ * E_ / 8);
  const int n8_ow = (int)((size_t)E_ * E_ / 8);
  const int cc0 = n8_q, cc1 = cc0 + n8_a, cc2 = cc1 + n8_pw, cc3 = cc2 + n8_iw,
            cc4 = cc3 + n8_ow;
  cast5<<<2048, 256, 0, stream>>>(query, query_bf, cc0,
                                  aug, aug_bf, cc1,
                                  projw, projw_bf, cc2,
                                  ipw, w_bf, cc3,
                                  opw, outw_bf, cc4);

  // projwT[AUG,E] = projw^T
  transpose_w<<<dim3(AUG_ / 64, E_ / 64), 256, 0, stream>>>(projw_bf, projwT, E_, AUG_);
  // Wkv[2E, AUG] = [wk; wv] @ projw  (weight-space fusion)
  gemm_bt2<0><<<dim3(AUG_ / 256, (2 * E_) / 256), 512, 0, stream>>>(
      w_bf + (size_t)E_ * E_, projwT, nullptr, wkv_f, nullptr, AUG_, E_);
  // bkv[2E] = [wk; wv] @ projb + ipb[E..3E]
  gemv_bias<<<2 * E_, 256, 0, stream>>>(w_bf + (size_t)E_ * E_, projb, ipb + E_, bkv, E_);

  // q = query @ wq^T + bq
  gemm_bt2<0><<<dim3(E_ / 256, M / 256), 512, 0, stream>>>(query_bf, w_bf, ipb, q_bf, nullptr, E_, E_);
  // merged k+vt: N=4096 over wkv_f; cols<2048 -> k row-major, cols>=2048 -> vt scatter
  gemm_bt2<3><<<dim3((2 * E_) / 256, M / 256), 512, 0, stream>>>(
      aug_bf, wkv_f, bkv, k_bf, vt_bf, 2 * E_, AUG_);
  // attention -> ctx  (QBLK=128 per block)
  attn_kernel<<<B_ * H_ * (LQ_ / 128), 256, 0, stream>>>(q_bf, k_bf, vt_bf, ctx_bf);
  // attn_out = ctx @ out_proj^T + b (bf16)
  gemm_bt2<0><<<dim3(E_ / 256, M / 256), 512, 0, stream>>>(ctx_bf, outw_bf, opb, attn_out, nullptr, E_, E_);
  // out = RMSNorm(attn_out)*(1+w) + query
  rms_res_bf<<<M, 256, 0, stream>>>(attn_out, rmsw, query, (float*)d_out);
}